// Round 11
// baseline (559.202 us; speedup 1.0000x reference)
//
#include <hip/hip_runtime.h>
#include <hip/hip_bf16.h>
#include <math.h>

typedef __bf16 bf16_t;
typedef __bf16 bf16x4 __attribute__((ext_vector_type(4)));
typedef __bf16 bf16x8 __attribute__((ext_vector_type(8)));
typedef float  f32x4  __attribute__((ext_vector_type(4)));

#define BB 4096
#define NN 2048
#define DD 1024
#define HH 4096
#define KSEL 5
#define NHEAD 8

__device__ __forceinline__ unsigned short bfbits(float f) {
  return __builtin_bit_cast(unsigned short, (bf16_t)f);
}

__device__ __forceinline__ void gload_lds16(const void* g, void* l) {
  __builtin_amdgcn_global_load_lds(
      (const __attribute__((address_space(1))) void*)g,
      (__attribute__((address_space(3))) void*)l, 16, 0, 0);
}

__device__ __forceinline__ ushort4 cvt4(float4 x) {
  ushort4 o;
  o.x = bfbits(x.x); o.y = bfbits(x.y); o.z = bfbits(x.z); o.w = bfbits(x.w);
  return o;
}

// ------- fused fp32->bf16 prep + rnorm (blocks >= 2048 do the fp64 row norms) -------
#define P_M0   1048576
#define P_S0   1572864
#define P_EVO  2097152
#define P_WQ   2359296
#define P_WKV  2883584
#define P_WO   3145728
#define P_W1   4194304
#define P_W2   8388608
#define P_W3   9437184
#define P_BKV  9437696
__global__ void __launch_bounds__(256)
prep_k(const float4* __restrict__ m0, const float4* __restrict__ s0,
       const float4* __restrict__ s1,
       const float4* __restrict__ wq, const float4* __restrict__ wk,
       const float4* __restrict__ wv, const float4* __restrict__ wo,
       const float4* __restrict__ w1, const float4* __restrict__ w2,
       const float4* __restrict__ w3,
       const float4* __restrict__ bk, const float4* __restrict__ bv,
       ushort4* __restrict__ m0b, ushort4* __restrict__ s0b,
       ushort4* __restrict__ evo,
       ushort4* __restrict__ wqb, ushort4* __restrict__ wkvb,
       ushort4* __restrict__ wob,
       ushort4* __restrict__ w1b, ushort4* __restrict__ w2b,
       ushort4* __restrict__ w3b, float4* __restrict__ bkv,
       double* __restrict__ rnd)
{
  __shared__ double red[256];
  const int tid = threadIdx.x;
  if (blockIdx.x >= 2048) {            // rnorm rows (one block per stored row)
    int n = blockIdx.x - 2048;
    float4 x = s0[(size_t)n * 256 + tid];
    double ss = (double)x.x * x.x + (double)x.y * x.y + (double)x.z * x.z + (double)x.w * x.w;
    red[tid] = ss; __syncthreads();
    for (int s = 128; s > 0; s >>= 1) {
      if (tid < s) red[tid] += red[tid + s];
      __syncthreads();
    }
    if (tid == 0) rnd[n] = 1.0 / fmax(sqrt(red[0]), 1e-12);
    return;
  }
  const int stride = 2048 * 256;
  for (int i = blockIdx.x * 256 + tid; i < P_BKV; i += stride) {
    if (i < P_M0) {
      m0b[i] = cvt4(m0[i]);
    } else if (i < P_S0) {
      int j = i - P_M0; s0b[j] = cvt4(s0[j]);
    } else if (i < P_EVO) {
      int j = i - P_S0;
      float4 a = s0[j], b = s1[j];
      float4 d; d.x = b.x - a.x; d.y = b.y - a.y; d.z = b.z - a.z; d.w = b.w - a.w;
      evo[j] = cvt4(d);
    } else if (i < P_WQ) {
      int j = i - P_EVO; wqb[j] = cvt4(wq[j]);
    } else if (i < P_WKV) {
      int j = i - P_WQ;                       // 0..524287: wk block then wv
      wkvb[j] = cvt4(j < 262144 ? wk[j] : wv[j - 262144]);
    } else if (i < P_WO) {
      int j = i - P_WKV; wob[j] = cvt4(wo[j]);
    } else if (i < P_W1) {
      int j = i - P_WO; w1b[j] = cvt4(w1[j]);
    } else if (i < P_W2) {
      int j = i - P_W1; w2b[j] = cvt4(w2[j]);
    } else if (i < P_W3) {
      int j = i - P_W2; w3b[j] = cvt4(w3[j]);
    } else {
      int j = i - P_W3;                       // concat(bk,bv)
      bkv[j] = (j < 256) ? bk[j] : bv[j - 256];
    }
  }
}

// ------- bf16 MFMA GEMM, 2-phase LDS double buffer (R9, conflict-free swizzle) -------
template<bool RELU, bool RESID, bool OUTBF16>
__global__ void __launch_bounds__(256)
gemm_bt(const bf16_t* __restrict__ A, const bf16_t* __restrict__ Bw,
        const float* __restrict__ bias, const float* __restrict__ resid,
        float* __restrict__ outf, bf16_t* __restrict__ outb,
        int M, int Nn, int Kk)
{
  __shared__ alignas(16) bf16_t At[2][4096];   // [buf][128 rows][32 k]
  __shared__ alignas(16) bf16_t Bt[2][4096];
  const int tid = threadIdx.x;
  const int wave = tid >> 6, lane = tid & 63;
  const int wm = wave >> 1, wn = wave & 1;
  const int bm = blockIdx.y << 7, bn = blockIdx.x << 7;
  const int ln15 = lane & 15, ln4 = lane >> 4;

  const int srow  = (wave << 4) + (lane >> 2);                 // 0..63
  const int scolb = (((lane & 3) ^ ((lane >> 3) & 3)) << 4);   // swizzled source slot
  const char* pA0 = (const char*)A  + (size_t)(bm + srow) * Kk * 2 + scolb;
  const char* pA1 = (const char*)A  + (size_t)(bm + srow + 64) * Kk * 2 + scolb;
  const char* pB0 = (const char*)Bw + (size_t)(bn + srow) * Kk * 2 + scolb;
  const char* pB1 = (const char*)Bw + (size_t)(bn + srow + 64) * Kk * 2 + scolb;

  f32x4 zero = {0.f, 0.f, 0.f, 0.f};
  f32x4 acc[4][4];
  #pragma unroll
  for (int i = 0; i < 4; ++i)
    #pragma unroll
    for (int j = 0; j < 4; ++j) acc[i][j] = zero;

  const int rslot = (ln4 ^ ((ln15 >> 1) & 3)) << 3;            // swizzled read slot (elems)
  const int fAoff = ((wm << 6) + ln15) * 32 + rslot;
  const int fBoff = ((wn << 6) + ln15) * 32 + rslot;

  const int nt = Kk >> 5;
  {
    char* lA = (char*)At[0] + (wave << 10);
    char* lB = (char*)Bt[0] + (wave << 10);
    gload_lds16(pA0, lA);
    gload_lds16(pA1, lA + 4096);
    gload_lds16(pB0, lB);
    gload_lds16(pB1, lB + 4096);
  }
  __syncthreads();

  for (int t = 0; t < nt; ++t) {
    const int cur = t & 1;
    if (t + 1 < nt) {
      size_t kb = (size_t)(t + 1) << 6;          // 64 bytes per K-step
      char* lA = (char*)At[cur ^ 1] + (wave << 10);
      char* lB = (char*)Bt[cur ^ 1] + (wave << 10);
      gload_lds16(pA0 + kb, lA);
      gload_lds16(pA1 + kb, lA + 4096);
      gload_lds16(pB0 + kb, lB);
      gload_lds16(pB1 + kb, lB + 4096);
    }
    bf16x8 av[4], bv[4];
    #pragma unroll
    for (int i = 0; i < 4; ++i) av[i] = *(const bf16x8*)(&At[cur][fAoff + i * 512]);
    #pragma unroll
    for (int j = 0; j < 4; ++j) bv[j] = *(const bf16x8*)(&Bt[cur][fBoff + j * 512]);
    #pragma unroll
    for (int i = 0; i < 4; ++i)
      #pragma unroll
      for (int j = 0; j < 4; ++j)
        acc[i][j] = __builtin_amdgcn_mfma_f32_16x16x32_bf16(av[i], bv[j], acc[i][j], 0, 0, 0);
    __syncthreads();
  }

  const int r0 = bm + (wm << 6) + ((lane >> 4) << 2);
  const int c0 = bn + (wn << 6) + ln15;
  #pragma unroll
  for (int i = 0; i < 4; ++i) {
    #pragma unroll
    for (int j = 0; j < 4; ++j) {
      #pragma unroll
      for (int r = 0; r < 4; ++r) {
        int row = r0 + i * 16 + r;
        int col = c0 + j * 16;
        size_t o = (size_t)row * Nn + col;
        float v = acc[i][j][r];
        if (bias)  v += bias[col];
        if (RESID) v += resid[o];
        if (RELU)  v = fmaxf(v, 0.f);
        if (OUTBF16) outb[o] = (bf16_t)v;
        else         outf[o] = v;
      }
    }
  }
}

// ------- 256x256 8-wave 8-phase schedule, single-read quadrant order (R11) -------
// Quadrants per K-tile: (0,0)->(0,1)->(1,1)->(1,0); both B-halves stay register-
// resident (bv0,bv1) so reads/phase = 12,4,8,0 = 24/wave/K-tile (R10's order re-read
// A0 -> 32). Stage map re-derived: ph1:A0(t+1)->buf1, ph2:B0(t+2)->buf0, ph3:B1(t+2),
// ph4:A1(t+2), ph5:A0(t+2), ph6:B0(t+3)->buf1, ph7:B1(t+3), ph8:A1(t+3). Every region
// is staged >=1 barrier after its last reader (B0 read ph1->st ph2; B1 read ph2->st ph3;
// A1 read ph3->st ph4; A0 read ph1->st ph5; buf1 symmetric ph5-8). vmcnt(6) at end of
// ph4/ph8 leaves exactly the newest 3 half-tiles in flight; everything the next 4 phases
// read has landed (verified by issue-order count: 14 outstanding -> oldest 8 land).
// Tail iter: ph4 gate degrades to vmcnt(0). Raw s_barrier only.
template<bool RELU>
__global__ void __launch_bounds__(512, 2)
gemm8(const bf16_t* __restrict__ A, const bf16_t* __restrict__ Bw,
      const float* __restrict__ bias, bf16_t* __restrict__ outb,
      int Nn, int Kk, int nbx)
{
  __shared__ alignas(16) bf16_t As[2][2][8192];   // [buf][mh][128*64]
  __shared__ alignas(16) bf16_t Bs[2][2][8192];   // [buf][nh][128*64]
  const int lane = threadIdx.x & 63, wv = threadIdx.x >> 6;
  const int wm = wv >> 2, wn = wv & 3;            // 2 x 4 waves, wave tile 128x64
  const int ln15 = lane & 15, ln4 = lane >> 4;

  // bijective XCD swizzle (m204)
  const int nwg = gridDim.x;
  const int q = nwg >> 3, r = nwg & 7;
  const int xcd = blockIdx.x & 7, loc = blockIdx.x >> 3;
  const int swz = (xcd < r ? xcd * (q + 1) : r * (q + 1) + (xcd - r) * q) + loc;
  const int bm = (swz / nbx) << 8;
  const int bn = (swz % nbx) << 8;

  const int NT = Kk >> 6;

  f32x4 acc[8][4];
  f32x4 zero = {0.f, 0.f, 0.f, 0.f};
  #pragma unroll
  for (int i = 0; i < 8; ++i)
    #pragma unroll
    for (int j = 0; j < 4; ++j) acc[i][j] = zero;

  auto stA = [&](int mh, int buf, int kt) {
    #pragma unroll
    for (int u = 0; u < 2; ++u) {
      int lr = u * 64 + wv * 8 + (lane >> 3);
      int gr = ((lr >> 6) << 7) | (mh << 6) | (lr & 63);
      int slot = (lane & 7) ^ (lr & 7);
      gload_lds16(A + (size_t)(bm + gr) * Kk + kt * 64 + slot * 8,
                  (char*)&As[buf][mh][0] + (u * 64 + wv * 8) * 128);
    }
  };
  auto stB = [&](int nh, int buf, int kt) {
    #pragma unroll
    for (int u = 0; u < 2; ++u) {
      int lr = u * 64 + wv * 8 + (lane >> 3);
      int gr = ((lr >> 5) << 6) | (nh << 5) | (lr & 31);
      int slot = (lane & 7) ^ (lr & 7);
      gload_lds16(Bw + (size_t)(bn + gr) * Kk + kt * 64 + slot * 8,
                  (char*)&Bs[buf][nh][0] + (u * 64 + wv * 8) * 128);
    }
  };

  // prologue: tile0 (B0,B1,A1,A0) + tile1 minus A0 -> 14 loads; vmcnt(6) lands tile0
  stB(0, 0, 0); stB(1, 0, 0); stA(1, 0, 0); stA(0, 0, 0);
  stB(0, 1, 1); stB(1, 1, 1); stA(1, 1, 1);
  asm volatile("s_waitcnt vmcnt(6)" ::: "memory");
  __builtin_amdgcn_s_barrier();

#define RD_A(MH, BF)                                                              \
    _Pragma("unroll") for (int mi = 0; mi < 4; ++mi)                              \
      _Pragma("unroll") for (int kk = 0; kk < 2; ++kk) {                          \
        const int lr = wm * 64 + mi * 16 + ln15;                                  \
        avv[mi][kk] = *(const bf16x8*)((const char*)&As[BF][MH][0] + lr * 128 +   \
                                       ((((kk << 2) | ln4) ^ (ln15 & 7)) << 4));  \
      }
#define RD_B(BV, NH, BF)                                                          \
    _Pragma("unroll") for (int nj = 0; nj < 2; ++nj)                              \
      _Pragma("unroll") for (int kk = 0; kk < 2; ++kk) {                          \
        const int lr = wn * 32 + nj * 16 + ln15;                                  \
        BV[nj][kk] = *(const bf16x8*)((const char*)&Bs[BF][NH][0] + lr * 128 +    \
                                      ((((kk << 2) | ln4) ^ (ln15 & 7)) << 4));   \
      }
#define GATE                                                                      \
    __builtin_amdgcn_s_barrier();                                                 \
    asm volatile("s_waitcnt lgkmcnt(0)" ::: "memory");                            \
    __builtin_amdgcn_sched_barrier(0);
#define MMA(MH, NH, BV)                                                           \
    __builtin_amdgcn_s_setprio(1);                                                \
    _Pragma("unroll") for (int kk = 0; kk < 2; ++kk)                              \
      _Pragma("unroll") for (int mi = 0; mi < 4; ++mi)                            \
        _Pragma("unroll") for (int nj = 0; nj < 2; ++nj)                          \
          acc[(MH)*4+mi][(NH)*2+nj] = __builtin_amdgcn_mfma_f32_16x16x32_bf16(    \
              avv[mi][kk], BV[nj][kk], acc[(MH)*4+mi][(NH)*2+nj], 0, 0, 0);       \
    __builtin_amdgcn_s_setprio(0);                                                \
    __builtin_amdgcn_s_barrier();

  for (int base = 0; base < NT; base += 2) {
    const bool more = (base + 2 < NT);
    bf16x8 avv[4][2], bv0[2][2], bv1[2][2];

    // ---- K-tile t = base (buf0) ----
    // ph1: Q(0,0); stage A0(t+1)->buf1
    RD_A(0, 0); RD_B(bv0, 0, 0);
    stA(0, 1, base + 1);
    asm volatile("s_waitcnt lgkmcnt(8)");
    GATE; MMA(0, 0, bv0);
    // ph2: Q(0,1); stage B0(t+2)->buf0
    RD_B(bv1, 1, 0);
    if (more) stB(0, 0, base + 2);
    GATE; MMA(0, 1, bv1);
    // ph3: Q(1,1); stage B1(t+2)->buf0
    RD_A(1, 0);
    if (more) stB(1, 0, base + 2);
    GATE; MMA(1, 1, bv1);
    // ph4: Q(1,0) (no reads); stage A1(t+2)->buf0; counted gate (drain in tail)
    if (more) {
      stA(1, 0, base + 2);
      asm volatile("s_waitcnt vmcnt(6)" ::: "memory");
    } else {
      asm volatile("s_waitcnt vmcnt(0)" ::: "memory");
    }
    GATE; MMA(1, 0, bv0);

    // ---- K-tile t+1 = base+1 (buf1) ----
    // ph5: Q(0,0); stage A0(t+2)->buf0
    RD_A(0, 1); RD_B(bv0, 0, 1);
    if (more) stA(0, 0, base + 2);
    asm volatile("s_waitcnt lgkmcnt(8)");
    GATE; MMA(0, 0, bv0);
    // ph6: Q(0,1); stage B0(t+3)->buf1
    RD_B(bv1, 1, 1);
    if (more) stB(0, 1, base + 3);
    GATE; MMA(0, 1, bv1);
    // ph7: Q(1,1); stage B1(t+3)->buf1
    RD_A(1, 1);
    if (more) stB(1, 1, base + 3);
    GATE; MMA(1, 1, bv1);
    // ph8: Q(1,0) (no reads); stage A1(t+3)->buf1; counted gate
    if (more) stA(1, 1, base + 3);
    asm volatile("s_waitcnt vmcnt(6)" ::: "memory");
    GATE; MMA(1, 0, bv0);
  }
#undef RD_A
#undef RD_B
#undef GATE
#undef MMA

  // epilogue: C/D layout col=lane&15, row=(lane>>4)*4+reg
  #pragma unroll
  for (int am = 0; am < 8; ++am) {
    #pragma unroll
    for (int an = 0; an < 4; ++an) {
      #pragma unroll
      for (int rr = 0; rr < 4; ++rr) {
        int row = bm + wm * 128 + (am >> 2) * 64 + (am & 3) * 16 + (lane >> 4) * 4 + rr;
        int col = bn + wn * 64 + (an >> 1) * 32 + (an & 1) * 16 + ln15;
        float v = acc[am][an][rr] + bias[col];
        if (RELU) v = fmaxf(v, 0.f);
        outb[(size_t)row * Nn + col] = (bf16_t)v;
      }
    }
  }
}

// ------- single-pass top-8 (per-thread sort + LDS tree merge) + fp64 re-rank -------
__global__ void __launch_bounds__(256)
topk_refine_k(const float* __restrict__ sim, const double* __restrict__ rnd,
              const float* __restrict__ m0, const float* __restrict__ s0,
              int* __restrict__ topidx)
{
  __shared__ float  lv[2][256][8];
  __shared__ int    li[2][256][8];
  __shared__ double dred[256];
  __shared__ double dvals[8];
  const int b = blockIdx.x, tid = threadIdx.x;

  // per-thread top-8 of its 8 strided elements (register insertion sort, desc (v, -idx))
  float tv[8]; int ti[8];
  #pragma unroll
  for (int p = 0; p < 8; ++p) { tv[p] = -INFINITY; ti[p] = NN; }
  #pragma unroll
  for (int t = 0; t < 8; ++t) {
    int i = tid + t * 256;
    float v = sim[(size_t)b * NN + i] * (float)rnd[i];
    int   ix = i;
    #pragma unroll
    for (int p = 0; p < 8; ++p) {
      bool better = (v > tv[p]) || (v == tv[p] && ix < ti[p]);
      if (better) {
        float sv = tv[p]; int si = ti[p];
        tv[p] = v; ti[p] = ix; v = sv; ix = si;
      }
    }
  }
  #pragma unroll
  for (int p = 0; p < 8; ++p) { lv[0][tid][p] = tv[p]; li[0][tid][p] = ti[p]; }
  __syncthreads();

  // tree merge: 8 levels, two-pointer merge of sorted-8 lists -> top-8 (double-buffered)
  int cur = 0;
  for (int s = 128; s > 0; s >>= 1) {
    if (tid < s) {
      int ia = 0, ib = 0;
      #pragma unroll
      for (int p = 0; p < 8; ++p) {
        float va = lv[cur][tid][ia],     vb = lv[cur][tid + s][ib];
        int   ja = li[cur][tid][ia],     jb = li[cur][tid + s][ib];
        bool ta = (va > vb) || (va == vb && ja < jb);
        lv[cur ^ 1][tid][p] = ta ? va : vb;
        li[cur ^ 1][tid][p] = ta ? ja : jb;
        if (ta) ++ia; else ++ib;
      }
    }
    __syncthreads();
    cur ^= 1;
  }
  // final top-8 (exact, (v desc, idx asc)) at lv/li[cur][0][0..7]
  int cs[8];
  #pragma unroll
  for (int j = 0; j < 8; ++j) cs[j] = li[cur][0][j];

  // fp64 re-rank of the 8 candidates
  const float* qrow = m0 + (size_t)b * DD;
  double part[8];
  #pragma unroll
  for (int j = 0; j < 8; ++j) part[j] = 0.0;
  for (int d = tid; d < DD; d += 256) {
    double qd = (double)qrow[d];
    #pragma unroll
    for (int j = 0; j < 8; ++j)
      part[j] += qd * (double)s0[(size_t)cs[j] * DD + d];
  }
  for (int j = 0; j < 8; ++j) {
    dred[tid] = part[j]; __syncthreads();
    for (int s = 128; s > 0; s >>= 1) {
      if (tid < s) dred[tid] += dred[tid + s];
      __syncthreads();
    }
    if (tid == 0) dvals[j] = dred[0] * rnd[cs[j]];
    __syncthreads();
  }
  if (tid == 0) {
    bool used[8] = {false,false,false,false,false,false,false,false};
    for (int p = 0; p < KSEL; ++p) {
      int best = -1;
      for (int j = 0; j < 8; ++j) {
        if (used[j]) continue;
        if (best < 0 || dvals[j] > dvals[best] ||
            (dvals[j] == dvals[best] && cs[j] < cs[best])) best = j;
      }
      used[best] = true;
      topidx[b * KSEL + p] = cs[best];
    }
  }
}

// ---- fused attention over merged eKV rows: ctx[d] = sum_j a_{head(d),j} * eV[idx_j][d] ----
__global__ void __launch_bounds__(256)
attn_k(const bf16_t* __restrict__ q, const bf16_t* __restrict__ eKV,
       const int* __restrict__ tidx,
       bf16_t* __restrict__ ctx, float* __restrict__ attn_out)
{
  __shared__ float aw[NHEAD][KSEL];
  const int b = blockIdx.x, t = threadIdx.x;
  const int d0 = t << 2;                 // 4 dims per thread; head = t>>5
  int idx[KSEL];
  #pragma unroll
  for (int j = 0; j < KSEL; ++j) idx[j] = tidx[b * KSEL + j];

  bf16x4 qv = *(const bf16x4*)(q + (size_t)b * DD + d0);
  float s[KSEL];
  #pragma unroll
  for (int j = 0; j < KSEL; ++j) {
    bf16x4 kv = *(const bf16x4*)(eKV + (size_t)idx[j] * 2048 + d0);
    float p = (float)qv[0] * (float)kv[0] + (float)qv[1] * (float)kv[1]
            + (float)qv[2] * (float)kv[2] + (float)qv[3] * (float)kv[3];
    #pragma unroll
    for (int m = 16; m > 0; m >>= 1) p += __shfl_xor(p, m);  // reduce 32-thread head group
    s[j] = p * 0.08838834764831845f;     // 1/sqrt(128)
  }
  float mx = s[0];
  #pragma unroll
  for (int j = 1; j < KSEL; ++j) mx = fmaxf(mx, s[j]);
  float e[KSEL], sum = 0.f;
  #pragma unroll
  for (int j = 0; j < KSEL; ++j) { e[j] = expf(s[j] - mx); sum += e[j]; }
  float inv = 1.f / sum;

  float c0 = 0.f, c1 = 0.f, c2 = 0.f, c3 = 0.f;
  #pragma unroll
  for (int j = 0; j < KSEL; ++j) {
    float a = e[j] * inv;
    bf16x4 vv = *(const bf16x4*)(eKV + (size_t)idx[j] * 2048 + 1024 + d0);
    c0 += a * (float)vv[0]; c1 += a * (float)vv[1];
    c2 += a * (float)vv[2]; c3 += a * (float)vv[3];
    if ((t & 31) == 0) aw[t >> 5][j] = a;
  }
  bf16x4 co; co[0] = (bf16_t)c0; co[1] = (bf16_t)c1; co[2] = (bf16_t)c2; co[3] = (bf16_t)c3;
  *(bf16x4*)(ctx + (size_t)b * DD + d0) = co;
  __syncthreads();
  if (t < KSEL) {
    float m = 0.f;
    #pragma unroll
    for (int hh = 0; hh < NHEAD; ++hh) m += aw[hh][t];
    attn_out[(size_t)b * KSEL + t] = m * 0.125f;
  }
}

// ---------------- launch ----------------
extern "C" void kernel_launch(void* const* d_in, const int* in_sizes, int n_in,
                              void* d_out, int out_size, void* d_ws, size_t ws_size,
                              hipStream_t stream) {
  (void)in_sizes; (void)n_in; (void)out_size; (void)ws_size;
  const float* morph0 = (const float*)d_in[0];
  const float* s0     = (const float*)d_in[1];
  const float* s1     = (const float*)d_in[2];
  const float* wq = (const float*)d_in[3];  const float* bq = (const float*)d_in[4];
  const float* wk = (const float*)d_in[5];  const float* bk = (const float*)d_in[6];
  const float* wv = (const float*)d_in[7];  const float* bv = (const float*)d_in[8];
  const float* wo = (const float*)d_in[9];  const float* bo = (const float*)d_in[10];
  const float* w1 = (const float*)d_in[11]; const float* b1 = (const float*)d_in[12];
  const float* w2 = (const float*)d_in[13]; const float* b2 = (const float*)d_in[14];
  const float* w3 = (const float*)d_in[15]; const float* b3 = (const float*)d_in[16];

  char* ws = (char*)d_ws;
  size_t off = 0;
  auto alloc = [&](size_t bytes) { char* p = ws + off; off += (bytes + 255) & ~(size_t)255; return p; };

  float*  sim  = (float*) alloc((size_t)BB * NN * 4);     // 33.5MB, reused as h1 (bf16) later
  bf16_t* m0b  = (bf16_t*)alloc((size_t)BB * DD * 2);
  bf16_t* s0b  = (bf16_t*)alloc((size_t)NN * DD * 2);
  bf16_t* evo  = (bf16_t*)alloc((size_t)NN * DD * 2);
  double* rnd  = (double*)alloc((size_t)NN * 8);
  int*    tidx = (int*)   alloc((size_t)BB * KSEL * 4);
  bf16_t* qb   = (bf16_t*)alloc((size_t)BB * DD * 2);
  bf16_t* eKVb = (bf16_t*)alloc((size_t)NN * 2048 * 2);
  bf16_t* ctxb = (bf16_t*)alloc((size_t)BB * DD * 2);
  bf16_t* xb   = (bf16_t*)alloc((size_t)BB * DD * 2);
  bf16_t* wqb  = (bf16_t*)alloc((size_t)DD * DD * 2);
  bf16_t* wkvb = (bf16_t*)alloc((size_t)2048 * DD * 2);
  bf16_t* wob  = (bf16_t*)alloc((size_t)DD * DD * 2);
  bf16_t* w1b  = (bf16_t*)alloc((size_t)HH * DD * 2);
  bf16_t* w2b  = (bf16_t*)alloc((size_t)HH * HH * 2);
  bf16_t* w3b  = (bf16_t*)alloc((size_t)DD * HH * 2);
  float*  bkv  = (float*) alloc((size_t)2048 * 4);
  bf16_t* h2b  = (bf16_t*)alloc((size_t)BB * HH * 2);
  bf16_t* h1b  = (bf16_t*)sim;  // alias: sim dead after topk; sizes match (33.5MB)
  float*  attn_out = (float*)d_out + (size_t)BB * DD;

  // fused prep: conversions + evo + merged wkv + bkv (blocks 0-2047) + rnorm (2048-4095)
  prep_k<<<dim3(4096), dim3(256), 0, stream>>>(
      (const float4*)morph0, (const float4*)s0, (const float4*)s1,
      (const float4*)wq, (const float4*)wk, (const float4*)wv, (const float4*)wo,
      (const float4*)w1, (const float4*)w2, (const float4*)w3,
      (const float4*)bk, (const float4*)bv,
      (ushort4*)m0b, (ushort4*)s0b, (ushort4*)evo,
      (ushort4*)wqb, (ushort4*)wkvb, (ushort4*)wob,
      (ushort4*)w1b, (ushort4*)w2b, (ushort4*)w3b, (float4*)bkv, rnd);

  // retrieval: sim GEMM, then fused single-pass top8 + fp64 refine
  gemm_bt<false,false,false><<<dim3(NN/128, BB/128), dim3(256), 0, stream>>>(
      m0b, s0b, nullptr, nullptr, sim, nullptr, BB, NN, DD);
  topk_refine_k<<<dim3(BB), dim3(256), 0, stream>>>(sim, rnd, morph0, s0, tidx);

  // projections: q on morph0; merged K|V on the 2048 unique evo rows
  gemm_bt<false,false,true><<<dim3(DD/128, BB/128), dim3(256), 0, stream>>>(
      m0b, wqb, bq, nullptr, nullptr, qb, BB, DD, DD);
  gemm_bt<false,false,true><<<dim3(2048/128, NN/128), dim3(256), 0, stream>>>(
      evo, wkvb, bkv, nullptr, nullptr, eKVb, NN, 2048, DD);

  // fused attention: scores, softmax, ctx (per-head weights in value space); attn_weights out
  attn_k<<<dim3(BB), dim3(256), 0, stream>>>(qb, eKVb, tidx, ctxb, attn_out);

  // out-proj + residual -> x
  gemm_bt<false,true,true><<<dim3(DD/128, BB/128), dim3(256), 0, stream>>>(
      ctxb, wob, bo, morph0, nullptr, xb, BB, DD, DD);

  // MLP: big square GEMMs on the 8-phase single-read kernel
  gemm8<true><<<dim3((BB/256)*(HH/256)), dim3(512), 0, stream>>>(
      xb, w1b, b1, h1b, HH, DD, HH/256);
  gemm8<true><<<dim3((BB/256)*(HH/256)), dim3(512), 0, stream>>>(
      h1b, w2b, b2, h2b, HH, HH, HH/256);
  gemm_bt<false,true,false><<<dim3(DD/128, BB/128), dim3(256), 0, stream>>>(
      h2b, w3b, b3, morph0, (float*)d_out, nullptr, BB, DD, HH);
}

// Round 12
// 499.168 us; speedup vs baseline: 1.1203x; 1.1203x over previous
//
#include <hip/hip_runtime.h>
#include <hip/hip_bf16.h>
#include <math.h>

typedef __bf16 bf16_t;
typedef __bf16 bf16x4 __attribute__((ext_vector_type(4)));
typedef __bf16 bf16x8 __attribute__((ext_vector_type(8)));
typedef float  f32x4  __attribute__((ext_vector_type(4)));

#define BB 4096
#define NN 2048
#define DD 1024
#define HH 4096
#define KSEL 5
#define NHEAD 8

__device__ __forceinline__ unsigned short bfbits(float f) {
  return __builtin_bit_cast(unsigned short, (bf16_t)f);
}

__device__ __forceinline__ void gload_lds16(const void* g, void* l) {
  __builtin_amdgcn_global_load_lds(
      (const __attribute__((address_space(1))) void*)g,
      (__attribute__((address_space(3))) void*)l, 16, 0, 0);
}

__device__ __forceinline__ ushort4 cvt4(float4 x) {
  ushort4 o;
  o.x = bfbits(x.x); o.y = bfbits(x.y); o.z = bfbits(x.z); o.w = bfbits(x.w);
  return o;
}

// ------- fused fp32->bf16 prep + rnorm (blocks >= 2048 do the fp64 row norms) -------
#define P_M0   1048576
#define P_S0   1572864
#define P_EVO  2097152
#define P_WQ   2359296
#define P_WKV  2883584
#define P_WO   3145728
#define P_W1   4194304
#define P_W2   8388608
#define P_W3   9437184
#define P_BKV  9437696
__global__ void __launch_bounds__(256)
prep_k(const float4* __restrict__ m0, const float4* __restrict__ s0,
       const float4* __restrict__ s1,
       const float4* __restrict__ wq, const float4* __restrict__ wk,
       const float4* __restrict__ wv, const float4* __restrict__ wo,
       const float4* __restrict__ w1, const float4* __restrict__ w2,
       const float4* __restrict__ w3,
       const float4* __restrict__ bk, const float4* __restrict__ bv,
       ushort4* __restrict__ m0b, ushort4* __restrict__ s0b,
       ushort4* __restrict__ evo,
       ushort4* __restrict__ wqb, ushort4* __restrict__ wkvb,
       ushort4* __restrict__ wob,
       ushort4* __restrict__ w1b, ushort4* __restrict__ w2b,
       ushort4* __restrict__ w3b, float4* __restrict__ bkv,
       double* __restrict__ rnd)
{
  __shared__ double red[256];
  const int tid = threadIdx.x;
  if (blockIdx.x >= 2048) {            // rnorm rows (one block per stored row)
    int n = blockIdx.x - 2048;
    float4 x = s0[(size_t)n * 256 + tid];
    double ss = (double)x.x * x.x + (double)x.y * x.y + (double)x.z * x.z + (double)x.w * x.w;
    red[tid] = ss; __syncthreads();
    for (int s = 128; s > 0; s >>= 1) {
      if (tid < s) red[tid] += red[tid + s];
      __syncthreads();
    }
    if (tid == 0) rnd[n] = 1.0 / fmax(sqrt(red[0]), 1e-12);
    return;
  }
  const int stride = 2048 * 256;
  for (int i = blockIdx.x * 256 + tid; i < P_BKV; i += stride) {
    if (i < P_M0) {
      m0b[i] = cvt4(m0[i]);
    } else if (i < P_S0) {
      int j = i - P_M0; s0b[j] = cvt4(s0[j]);
    } else if (i < P_EVO) {
      int j = i - P_S0;
      float4 a = s0[j], b = s1[j];
      float4 d; d.x = b.x - a.x; d.y = b.y - a.y; d.z = b.z - a.z; d.w = b.w - a.w;
      evo[j] = cvt4(d);
    } else if (i < P_WQ) {
      int j = i - P_EVO; wqb[j] = cvt4(wq[j]);
    } else if (i < P_WKV) {
      int j = i - P_WQ;                       // 0..524287: wk block then wv
      wkvb[j] = cvt4(j < 262144 ? wk[j] : wv[j - 262144]);
    } else if (i < P_WO) {
      int j = i - P_WKV; wob[j] = cvt4(wo[j]);
    } else if (i < P_W1) {
      int j = i - P_WO; w1b[j] = cvt4(w1[j]);
    } else if (i < P_W2) {
      int j = i - P_W1; w2b[j] = cvt4(w2[j]);
    } else if (i < P_W3) {
      int j = i - P_W2; w3b[j] = cvt4(w3[j]);
    } else {
      int j = i - P_W3;                       // concat(bk,bv)
      bkv[j] = (j < 256) ? bk[j] : bv[j - 256];
    }
  }
}

// ------- bf16 MFMA GEMM, 2-phase LDS double buffer (R9, conflict-free swizzle) -------
template<bool RELU, bool RESID, bool OUTBF16>
__global__ void __launch_bounds__(256)
gemm_bt(const bf16_t* __restrict__ A, const bf16_t* __restrict__ Bw,
        const float* __restrict__ bias, const float* __restrict__ resid,
        float* __restrict__ outf, bf16_t* __restrict__ outb,
        int M, int Nn, int Kk)
{
  __shared__ alignas(16) bf16_t At[2][4096];   // [buf][128 rows][32 k]
  __shared__ alignas(16) bf16_t Bt[2][4096];
  const int tid = threadIdx.x;
  const int wave = tid >> 6, lane = tid & 63;
  const int wm = wave >> 1, wn = wave & 1;
  const int bm = blockIdx.y << 7, bn = blockIdx.x << 7;
  const int ln15 = lane & 15, ln4 = lane >> 4;

  const int srow  = (wave << 4) + (lane >> 2);                 // 0..63
  const int scolb = (((lane & 3) ^ ((lane >> 3) & 3)) << 4);   // swizzled source slot
  const char* pA0 = (const char*)A  + (size_t)(bm + srow) * Kk * 2 + scolb;
  const char* pA1 = (const char*)A  + (size_t)(bm + srow + 64) * Kk * 2 + scolb;
  const char* pB0 = (const char*)Bw + (size_t)(bn + srow) * Kk * 2 + scolb;
  const char* pB1 = (const char*)Bw + (size_t)(bn + srow + 64) * Kk * 2 + scolb;

  f32x4 zero = {0.f, 0.f, 0.f, 0.f};
  f32x4 acc[4][4];
  #pragma unroll
  for (int i = 0; i < 4; ++i)
    #pragma unroll
    for (int j = 0; j < 4; ++j) acc[i][j] = zero;

  const int rslot = (ln4 ^ ((ln15 >> 1) & 3)) << 3;            // swizzled read slot (elems)
  const int fAoff = ((wm << 6) + ln15) * 32 + rslot;
  const int fBoff = ((wn << 6) + ln15) * 32 + rslot;

  const int nt = Kk >> 5;
  {
    char* lA = (char*)At[0] + (wave << 10);
    char* lB = (char*)Bt[0] + (wave << 10);
    gload_lds16(pA0, lA);
    gload_lds16(pA1, lA + 4096);
    gload_lds16(pB0, lB);
    gload_lds16(pB1, lB + 4096);
  }
  __syncthreads();

  for (int t = 0; t < nt; ++t) {
    const int cur = t & 1;
    if (t + 1 < nt) {
      size_t kb = (size_t)(t + 1) << 6;          // 64 bytes per K-step
      char* lA = (char*)At[cur ^ 1] + (wave << 10);
      char* lB = (char*)Bt[cur ^ 1] + (wave << 10);
      gload_lds16(pA0 + kb, lA);
      gload_lds16(pA1 + kb, lA + 4096);
      gload_lds16(pB0 + kb, lB);
      gload_lds16(pB1 + kb, lB + 4096);
    }
    bf16x8 av[4], bv[4];
    #pragma unroll
    for (int i = 0; i < 4; ++i) av[i] = *(const bf16x8*)(&At[cur][fAoff + i * 512]);
    #pragma unroll
    for (int j = 0; j < 4; ++j) bv[j] = *(const bf16x8*)(&Bt[cur][fBoff + j * 512]);
    #pragma unroll
    for (int i = 0; i < 4; ++i)
      #pragma unroll
      for (int j = 0; j < 4; ++j)
        acc[i][j] = __builtin_amdgcn_mfma_f32_16x16x32_bf16(av[i], bv[j], acc[i][j], 0, 0, 0);
    __syncthreads();
  }

  const int r0 = bm + (wm << 6) + ((lane >> 4) << 2);
  const int c0 = bn + (wn << 6) + ln15;
  #pragma unroll
  for (int i = 0; i < 4; ++i) {
    #pragma unroll
    for (int j = 0; j < 4; ++j) {
      #pragma unroll
      for (int r = 0; r < 4; ++r) {
        int row = r0 + i * 16 + r;
        int col = c0 + j * 16;
        size_t o = (size_t)row * Nn + col;
        float v = acc[i][j][r];
        if (bias)  v += bias[col];
        if (RESID) v += resid[o];
        if (RELU)  v = fmaxf(v, 0.f);
        if (OUTBF16) outb[o] = (bf16_t)v;
        else         outf[o] = v;
      }
    }
  }
}

// ------- 256x256 8-wave, interleaved-issue pipeline (R12) -------
// One barrier per K-tile (R7-proven hazard logic: reads hit buf[cur], stages write
// buf[cur^1]; per-wave vmcnt(0) + s_barrier publishes before any read of t+1).
// R5-R11 all serialized LDS-read bursts vs MFMA bursts (per-wave in-order issue +
// lockstep phases). Here reads/stages are dependence-placed INSIDE the 8 MFMA
// clusters (8 MFMA each, ks-split) and sched_group_barrier forces the interleave,
// so the wave alternates issue between the LDS pipe and the MFMA pipe:
//   pre: rd ae(k0)[4], b0k0[2]; stage A0,B0(t+1)[4]
//   c1 (0,0,k0) x8  + rd b1k0[2], ao(k0)[4]
//   c2 (0,1,k0) x8
//   c3 (1,1,k0) x8  + rd ae(k1)[4]          (WAR opens after c2)
//   c4 (1,0,k0) x8  + rd b1k1[2], stage A1,B1(t+1)[4]
//   c5 (0,1,k1) x8  + rd b0k1[2]            (b0k0 last used c4)
//   c6 (0,0,k1) x8  + rd ao(k1)[4]          (ao k0 last used c4)
//   c7 (1,0,k1) x8 ; c8 (1,1,k1) x8 ; vmcnt(0); s_barrier
// 24 ds_read + 8 gload + 64 MFMA per wave per tile; LDS BW needed ~79 B/cyc < 85.
#define SGB_M(n) __builtin_amdgcn_sched_group_barrier(0x008, n, 0)
#define SGB_D(n) __builtin_amdgcn_sched_group_barrier(0x100, n, 0)
#define SGB_V(n) __builtin_amdgcn_sched_group_barrier(0x020, n, 0)
template<bool RELU>
__global__ void __launch_bounds__(512, 2)
gemm8(const bf16_t* __restrict__ A, const bf16_t* __restrict__ Bw,
      const float* __restrict__ bias, bf16_t* __restrict__ outb,
      int Nn, int Kk, int nbx)
{
  __shared__ alignas(16) bf16_t As[2][2][8192];   // [buf][mh][128*64]
  __shared__ alignas(16) bf16_t Bs[2][2][8192];   // [buf][nh][128*64]
  const int lane = threadIdx.x & 63, wv = threadIdx.x >> 6;
  const int wm = wv >> 2, wn = wv & 3;            // 2 x 4 waves, wave tile 128x64
  const int ln15 = lane & 15, ln4 = lane >> 4;

  // bijective XCD swizzle (m204)
  const int nwg = gridDim.x;
  const int q = nwg >> 3, r = nwg & 7;
  const int xcd = blockIdx.x & 7, loc = blockIdx.x >> 3;
  const int swz = (xcd < r ? xcd * (q + 1) : r * (q + 1) + (xcd - r) * q) + loc;
  const int bm = (swz / nbx) << 8;
  const int bn = (swz % nbx) << 8;

  const int NT = Kk >> 6;

  f32x4 acc[8][4];
  f32x4 zero = {0.f, 0.f, 0.f, 0.f};
  #pragma unroll
  for (int i = 0; i < 8; ++i)
    #pragma unroll
    for (int j = 0; j < 4; ++j) acc[i][j] = zero;

  auto stA = [&](int mh, int buf, int kt) {
    #pragma unroll
    for (int u = 0; u < 2; ++u) {
      int lr = u * 64 + wv * 8 + (lane >> 3);
      int gr = ((lr >> 6) << 7) | (mh << 6) | (lr & 63);
      int slot = (lane & 7) ^ (lr & 7);
      gload_lds16(A + (size_t)(bm + gr) * Kk + kt * 64 + slot * 8,
                  (char*)&As[buf][mh][0] + (u * 64 + wv * 8) * 128);
    }
  };
  auto stB = [&](int nh, int buf, int kt) {
    #pragma unroll
    for (int u = 0; u < 2; ++u) {
      int lr = u * 64 + wv * 8 + (lane >> 3);
      int gr = ((lr >> 5) << 6) | (nh << 5) | (lr & 31);
      int slot = (lane & 7) ^ (lr & 7);
      gload_lds16(Bw + (size_t)(bn + gr) * Kk + kt * 64 + slot * 8,
                  (char*)&Bs[buf][nh][0] + (u * 64 + wv * 8) * 128);
    }
  };

  // prologue: full tile 0 into buf0, hard drain
  stA(0, 0, 0); stA(1, 0, 0); stB(0, 0, 0); stB(1, 0, 0);
  asm volatile("s_waitcnt vmcnt(0)" ::: "memory");
  __builtin_amdgcn_s_barrier();
  __builtin_amdgcn_sched_barrier(0);

#define RD_A4(AV, MH, KK, BF)                                                     \
    _Pragma("unroll") for (int mi = 0; mi < 4; ++mi) {                            \
      const int lr = wm * 64 + mi * 16 + ln15;                                    \
      AV[mi] = *(const bf16x8*)((const char*)&As[BF][MH][0] + lr * 128 +          \
                                (((((KK) << 2) | ln4) ^ (ln15 & 7)) << 4));       \
    }
#define RD_B2(BV, NH, KK, BF)                                                     \
    _Pragma("unroll") for (int nj = 0; nj < 2; ++nj) {                            \
      const int lr = wn * 32 + nj * 16 + ln15;                                    \
      BV[nj] = *(const bf16x8*)((const char*)&Bs[BF][NH][0] + lr * 128 +          \
                                (((((KK) << 2) | ln4) ^ (ln15 & 7)) << 4));       \
    }
#define MMA8(AV, BV, MH, NH)                                                      \
    _Pragma("unroll") for (int mi = 0; mi < 4; ++mi)                              \
      _Pragma("unroll") for (int nj = 0; nj < 2; ++nj)                            \
        acc[(MH)*4+mi][(NH)*2+nj] = __builtin_amdgcn_mfma_f32_16x16x32_bf16(      \
            AV[mi], BV[nj], acc[(MH)*4+mi][(NH)*2+nj], 0, 0, 0);

  // main loop: NT-1 tiles with unconditional stage of t+1 (no branches in region)
  for (int t = 0; t < NT - 1; ++t) {
    const int cur = t & 1, nb = cur ^ 1;
    bf16x8 ae[4], ao[4], b0k0[2], b1k0[2], b0k1[2], b1k1[2];

    RD_A4(ae, 0, 0, cur); RD_B2(b0k0, 0, 0, cur);
    stA(0, nb, t + 1); stB(0, nb, t + 1);
    SGB_D(6); SGB_V(4);
    // c1 (0,0,k0) + b1k0, ao(k0)
    RD_B2(b1k0, 1, 0, cur); RD_A4(ao, 1, 0, cur);
    MMA8(ae, b0k0, 0, 0);
    #pragma unroll
    for (int i = 0; i < 6; ++i) { SGB_M(1); SGB_D(1); }
    SGB_M(2);
    // c2 (0,1,k0)
    MMA8(ae, b1k0, 0, 1);
    SGB_M(8);
    // c3 (1,1,k0) + ae(k1)
    RD_A4(ae, 0, 1, cur);
    MMA8(ao, b1k0, 1, 1);
    #pragma unroll
    for (int i = 0; i < 4; ++i) { SGB_M(2); SGB_D(1); }
    // c4 (1,0,k0) + b1k1 + stages A1,B1
    RD_B2(b1k1, 1, 1, cur);
    stA(1, nb, t + 1); stB(1, nb, t + 1);
    MMA8(ao, b0k0, 1, 0);
    SGB_M(1); SGB_D(1); SGB_M(1); SGB_D(1);
    #pragma unroll
    for (int i = 0; i < 4; ++i) { SGB_M(1); SGB_V(1); }
    SGB_M(2);
    // c5 (0,1,k1) + b0k1
    RD_B2(b0k1, 0, 1, cur);
    MMA8(ae, b1k1, 0, 1);
    SGB_M(3); SGB_D(1); SGB_M(3); SGB_D(1); SGB_M(2);
    // c6 (0,0,k1) + ao(k1)
    RD_A4(ao, 1, 1, cur);
    MMA8(ae, b0k1, 0, 0);
    #pragma unroll
    for (int i = 0; i < 4; ++i) { SGB_M(2); SGB_D(1); }
    // c7, c8
    MMA8(ao, b0k1, 1, 0);
    SGB_M(8);
    MMA8(ao, b1k1, 1, 1);
    SGB_M(8);
    // tile boundary: own stages drained, publish
    asm volatile("s_waitcnt vmcnt(0)" ::: "memory");
    __builtin_amdgcn_sched_barrier(0);
    __builtin_amdgcn_s_barrier();
    __builtin_amdgcn_sched_barrier(0);
  }

  // tail tile: compute only
  {
    const int cur = (NT - 1) & 1;
    bf16x8 ae[4], ao[4], b0k0[2], b1k0[2], b0k1[2], b1k1[2];
    RD_A4(ae, 0, 0, cur); RD_B2(b0k0, 0, 0, cur);
    RD_B2(b1k0, 1, 0, cur); RD_A4(ao, 1, 0, cur);
    MMA8(ae, b0k0, 0, 0);
    MMA8(ae, b1k0, 0, 1);
    RD_A4(ae, 0, 1, cur);
    MMA8(ao, b1k0, 1, 1);
    RD_B2(b1k1, 1, 1, cur);
    MMA8(ao, b0k0, 1, 0);
    RD_B2(b0k1, 0, 1, cur);
    MMA8(ae, b1k1, 0, 1);
    RD_A4(ao, 1, 1, cur);
    MMA8(ae, b0k1, 0, 0);
    MMA8(ao, b0k1, 1, 0);
    MMA8(ao, b1k1, 1, 1);
  }
#undef RD_A4
#undef RD_B2
#undef MMA8

  // epilogue: C/D layout col=lane&15, row=(lane>>4)*4+reg
  #pragma unroll
  for (int am = 0; am < 8; ++am) {
    #pragma unroll
    for (int an = 0; an < 4; ++an) {
      #pragma unroll
      for (int rr = 0; rr < 4; ++rr) {
        int row = bm + wm * 128 + (am >> 2) * 64 + (am & 3) * 16 + (lane >> 4) * 4 + rr;
        int col = bn + wn * 64 + (an >> 1) * 32 + (an & 1) * 16 + ln15;
        float v = acc[am][an][rr] + bias[col];
        if (RELU) v = fmaxf(v, 0.f);
        outb[(size_t)row * Nn + col] = (bf16_t)v;
      }
    }
  }
}
#undef SGB_M
#undef SGB_D
#undef SGB_V

// ------- fused approx top-8 + fp64 re-rank -> exact top-5 (R10 version) -------
__global__ void __launch_bounds__(256)
topk_refine_k(const float* __restrict__ sim, const double* __restrict__ rnd,
              const float* __restrict__ m0, const float* __restrict__ s0,
              int* __restrict__ topidx)
{
  __shared__ float vals[NN];
  __shared__ float rv[256];
  __shared__ int   ri[256];
  __shared__ int   c8[8];
  __shared__ double dred[256];
  __shared__ double dvals[8];
  const int b = blockIdx.x, tid = threadIdx.x;
  for (int t = 0; t < NN / 256; ++t) {
    int i = tid + t * 256;
    vals[i] = sim[(size_t)b * NN + i] * (float)rnd[i];
  }
  __syncthreads();
  for (int p = 0; p < 8; ++p) {
    float bvv = -INFINITY; int bi = NN;
    for (int t = 0; t < NN / 256; ++t) {
      int i = tid + t * 256;
      float v = vals[i];
      if (v > bvv) { bvv = v; bi = i; }   // strict > keeps lowest index
    }
    rv[tid] = bvv; ri[tid] = bi;
    __syncthreads();
    for (int s = 128; s > 0; s >>= 1) {
      if (tid < s) {
        float v2 = rv[tid + s]; int i2 = ri[tid + s];
        if (v2 > rv[tid] || (v2 == rv[tid] && i2 < ri[tid])) { rv[tid] = v2; ri[tid] = i2; }
      }
      __syncthreads();
    }
    if (tid == 0) {
      int wsel = ri[0];
      c8[p] = wsel;
      vals[wsel] = -INFINITY;
    }
    __syncthreads();
  }
  int cs[8];
  #pragma unroll
  for (int j = 0; j < 8; ++j) cs[j] = c8[j];
  const float* qrow = m0 + (size_t)b * DD;
  double part[8];
  #pragma unroll
  for (int j = 0; j < 8; ++j) part[j] = 0.0;
  for (int d = tid; d < DD; d += 256) {
    double qd = (double)qrow[d];
    #pragma unroll
    for (int j = 0; j < 8; ++j)
      part[j] += qd * (double)s0[(size_t)cs[j] * DD + d];
  }
  for (int j = 0; j < 8; ++j) {
    dred[tid] = part[j]; __syncthreads();
    for (int s = 128; s > 0; s >>= 1) {
      if (tid < s) dred[tid] += dred[tid + s];
      __syncthreads();
    }
    if (tid == 0) dvals[j] = dred[0] * rnd[cs[j]];
    __syncthreads();
  }
  if (tid == 0) {
    bool used[8] = {false,false,false,false,false,false,false,false};
    for (int p = 0; p < KSEL; ++p) {
      int best = -1;
      for (int j = 0; j < 8; ++j) {
        if (used[j]) continue;
        if (best < 0 || dvals[j] > dvals[best] ||
            (dvals[j] == dvals[best] && cs[j] < cs[best])) best = j;
      }
      used[best] = true;
      topidx[b * KSEL + p] = cs[best];
    }
  }
}

// ---- fused attention over merged eKV rows: ctx[d] = sum_j a_{head(d),j} * eV[idx_j][d] ----
__global__ void __launch_bounds__(256)
attn_k(const bf16_t* __restrict__ q, const bf16_t* __restrict__ eKV,
       const int* __restrict__ tidx,
       bf16_t* __restrict__ ctx, float* __restrict__ attn_out)
{
  __shared__ float aw[NHEAD][KSEL];
  const int b = blockIdx.x, t = threadIdx.x;
  const int d0 = t << 2;                 // 4 dims per thread; head = t>>5
  int idx[KSEL];
  #pragma unroll
  for (int j = 0; j < KSEL; ++j) idx[j] = tidx[b * KSEL + j];

  bf16x4 qv = *(const bf16x4*)(q + (size_t)b * DD + d0);
  float s[KSEL];
  #pragma unroll
  for (int j = 0; j < KSEL; ++j) {
    bf16x4 kv = *(const bf16x4*)(eKV + (size_t)idx[j] * 2048 + d0);
    float p = (float)qv[0] * (float)kv[0] + (float)qv[1] * (float)kv[1]
            + (float)qv[2] * (float)kv[2] + (float)qv[3] * (float)kv[3];
    #pragma unroll
    for (int m = 16; m > 0; m >>= 1) p += __shfl_xor(p, m);  // reduce 32-thread head group
    s[j] = p * 0.08838834764831845f;     // 1/sqrt(128)
  }
  float mx = s[0];
  #pragma unroll
  for (int j = 1; j < KSEL; ++j) mx = fmaxf(mx, s[j]);
  float e[KSEL], sum = 0.f;
  #pragma unroll
  for (int j = 0; j < KSEL; ++j) { e[j] = expf(s[j] - mx); sum += e[j]; }
  float inv = 1.f / sum;

  float c0 = 0.f, c1 = 0.f, c2 = 0.f, c3 = 0.f;
  #pragma unroll
  for (int j = 0; j < KSEL; ++j) {
    float a = e[j] * inv;
    bf16x4 vv = *(const bf16x4*)(eKV + (size_t)idx[j] * 2048 + 1024 + d0);
    c0 += a * (float)vv[0]; c1 += a * (float)vv[1];
    c2 += a * (float)vv[2]; c3 += a * (float)vv[3];
    if ((t & 31) == 0) aw[t >> 5][j] = a;
  }
  bf16x4 co; co[0] = (bf16_t)c0; co[1] = (bf16_t)c1; co[2] = (bf16_t)c2; co[3] = (bf16_t)c3;
  *(bf16x4*)(ctx + (size_t)b * DD + d0) = co;
  __syncthreads();
  if (t < KSEL) {
    float m = 0.f;
    #pragma unroll
    for (int hh = 0; hh < NHEAD; ++hh) m += aw[hh][t];
    attn_out[(size_t)b * KSEL + t] = m * 0.125f;
  }
}

// ---------------- launch ----------------
extern "C" void kernel_launch(void* const* d_in, const int* in_sizes, int n_in,
                              void* d_out, int out_size, void* d_ws, size_t ws_size,
                              hipStream_t stream) {
  (void)in_sizes; (void)n_in; (void)out_size; (void)ws_size;
  const float* morph0 = (const float*)d_in[0];
  const float* s0     = (const float*)d_in[1];
  const float* s1     = (const float*)d_in[2];
  const float* wq = (const float*)d_in[3];  const float* bq = (const float*)d_in[4];
  const float* wk = (const float*)d_in[5];  const float* bk = (const float*)d_in[6];
  const float* wv = (const float*)d_in[7];  const float* bv = (const float*)d_in[8];
  const float* wo = (const float*)d_in[9];  const float* bo = (const float*)d_in[10];
  const float* w1 = (const float*)d_in[11]; const float* b1 = (const float*)d_in[12];
  const float* w2 = (const float*)d_in[13]; const float* b2 = (const float*)d_in[14];
  const float* w3 = (const float*)d_in[15]; const float* b3 = (const float*)d_in[16];

  char* ws = (char*)d_ws;
  size_t off = 0;
  auto alloc = [&](size_t bytes) { char* p = ws + off; off += (bytes + 255) & ~(size_t)255; return p; };

  float*  sim  = (float*) alloc((size_t)BB * NN * 4);     // 33.5MB, reused as h1 (bf16) later
  bf16_t* m0b  = (bf16_t*)alloc((size_t)BB * DD * 2);
  bf16_t* s0b  = (bf16_t*)alloc((size_t)NN * DD * 2);
  bf16_t* evo  = (bf16_t*)alloc((size_t)NN * DD * 2);
  double* rnd  = (double*)alloc((size_t)NN * 8);
  int*    tidx = (int*)   alloc((size_t)BB * KSEL * 4);
  bf16_t* qb   = (bf16_t*)alloc((size_t)BB * DD * 2);
  bf16_t* eKVb = (bf16_t*)alloc((size_t)NN * 2048 * 2);
  bf16_t* ctxb = (bf16_t*)alloc((size_t)BB * DD * 2);
  bf16_t* xb   = (bf16_t*)alloc((size_t)BB * DD * 2);
  bf16_t* wqb  = (bf16_t*)alloc((size_t)DD * DD * 2);
  bf16_t* wkvb = (bf16_t*)alloc((size_t)2048 * DD * 2);
  bf16_t* wob  = (bf16_t*)alloc((size_t)DD * DD * 2);
  bf16_t* w1b  = (bf16_t*)alloc((size_t)HH * DD * 2);
  bf16_t* w2b  = (bf16_t*)alloc((size_t)HH * HH * 2);
  bf16_t* w3b  = (bf16_t*)alloc((size_t)DD * HH * 2);
  float*  bkv  = (float*) alloc((size_t)2048 * 4);
  bf16_t* h2b  = (bf16_t*)alloc((size_t)BB * HH * 2);
  bf16_t* h1b  = (bf16_t*)sim;  // alias: sim dead after topk; sizes match (33.5MB)
  float*  attn_out = (float*)d_out + (size_t)BB * DD;

  // fused prep: conversions + evo + merged wkv + bkv (blocks 0-2047) + rnorm (2048-4095)
  prep_k<<<dim3(4096), dim3(256), 0, stream>>>(
      (const float4*)morph0, (const float4*)s0, (const float4*)s1,
      (const float4*)wq, (const float4*)wk, (const float4*)wv, (const float4*)wo,
      (const float4*)w1, (const float4*)w2, (const float4*)w3,
      (const float4*)bk, (const float4*)bv,
      (ushort4*)m0b, (ushort4*)s0b, (ushort4*)evo,
      (ushort4*)wqb, (ushort4*)wkvb, (ushort4*)wob,
      (ushort4*)w1b, (ushort4*)w2b, (ushort4*)w3b, (float4*)bkv, rnd);

  // retrieval: sim GEMM, then fused top8+fp64 refine
  gemm_bt<false,false,false><<<dim3(NN/128, BB/128), dim3(256), 0, stream>>>(
      m0b, s0b, nullptr, nullptr, sim, nullptr, BB, NN, DD);
  topk_refine_k<<<dim3(BB), dim3(256), 0, stream>>>(sim, rnd, morph0, s0, tidx);

  // projections: q on morph0; merged K|V on the 2048 unique evo rows
  gemm_bt<false,false,true><<<dim3(DD/128, BB/128), dim3(256), 0, stream>>>(
      m0b, wqb, bq, nullptr, nullptr, qb, BB, DD, DD);
  gemm_bt<false,false,true><<<dim3(2048/128, NN/128), dim3(256), 0, stream>>>(
      evo, wkvb, bkv, nullptr, nullptr, eKVb, NN, 2048, DD);

  // fused attention: scores, softmax, ctx (per-head weights in value space); attn_weights out
  attn_k<<<dim3(BB), dim3(256), 0, stream>>>(qb, eKVb, tidx, ctxb, attn_out);

  // out-proj + residual -> x
  gemm_bt<false,true,true><<<dim3(DD/128, BB/128), dim3(256), 0, stream>>>(
      ctxb, wob, bo, morph0, nullptr, xb, BB, DD, DD);

  // MLP: big square GEMMs on the interleaved-issue kernel
  gemm8<true><<<dim3((BB/256)*(HH/256)), dim3(512), 0, stream>>>(
      xb, w1b, b1, h1b, HH, DD, HH/256);
  gemm8<true><<<dim3((BB/256)*(HH/256)), dim3(512), 0, stream>>>(
      h1b, w2b, b2, h2b, HH, HH, HH/256);
  gemm_bt<false,true,false><<<dim3(DD/128, BB/128), dim3(256), 0, stream>>>(
      h2b, w3b, b3, morph0, (float*)d_out, nullptr, BB, DD, HH);
}